// Round 1
// baseline (2110.847 us; speedup 1.0000x reference)
//
#include <hip/hip_runtime.h>
#include <stdint.h>

// ---- JAX Threefry mode: 1 = jax_threefry_partitionable=True (modern JAX default),
//                         0 = legacy iota-halved mode. Flip if masks mismatch.
#define JAX_PARTITIONABLE 1

static const int kN = 50000;
static const int kD = 64;
static const int kE = 800000;

#define TFR(x0, x1, r)                                    \
  {                                                       \
    x0 += x1;                                             \
    x1 = ((x1 << (r)) | (x1 >> (32 - (r))));              \
    x1 ^= x0;                                             \
  }

// Threefry-2x32, 20 rounds, JAX/Random123 key schedule. Bit-exact vs jax.random.
__host__ __device__ inline void tf2x32(uint32_t k0, uint32_t k1, uint32_t x0,
                                       uint32_t x1, uint32_t* o0, uint32_t* o1) {
  uint32_t k2 = k0 ^ k1 ^ 0x1BD11BDAu;
  x0 += k0; x1 += k1;
  TFR(x0, x1, 13) TFR(x0, x1, 15) TFR(x0, x1, 26) TFR(x0, x1, 6)
  x0 += k1; x1 += k2 + 1u;
  TFR(x0, x1, 17) TFR(x0, x1, 29) TFR(x0, x1, 16) TFR(x0, x1, 24)
  x0 += k2; x1 += k0 + 2u;
  TFR(x0, x1, 13) TFR(x0, x1, 15) TFR(x0, x1, 26) TFR(x0, x1, 6)
  x0 += k0; x1 += k1 + 3u;
  TFR(x0, x1, 17) TFR(x0, x1, 29) TFR(x0, x1, 16) TFR(x0, x1, 24)
  x0 += k1; x1 += k2 + 4u;
  TFR(x0, x1, 13) TFR(x0, x1, 15) TFR(x0, x1, 26) TFR(x0, x1, 6)
  x0 += k2; x1 += k0 + 5u;
  *o0 = x0; *o1 = x1;
}

__device__ inline float jax_uniform01(uint32_t bits) {
  return __uint_as_float((bits >> 9) | 0x3f800000u) - 1.0f;
}

__global__ void init_k(const int* __restrict__ x, const float* __restrict__ w,
                       float* __restrict__ hA, float* __restrict__ acc) {
  int idx = blockIdx.x * blockDim.x + threadIdx.x;
  if (idx >= kN * kD) return;
  int n = idx >> 6, d = idx & 63;
  float v = w[(size_t)x[n] * kD + d];
  hA[idx] = v;
  acc[idx] = v;
}

__global__ void dropout_k(const float* __restrict__ in, float* __restrict__ out,
                          uint32_t k0, uint32_t k1) {
  int idx = blockIdx.x * blockDim.x + threadIdx.x;
  if (idx >= kN * kD) return;
  uint32_t bits;
#if JAX_PARTITIONABLE
  uint32_t a, b;
  tf2x32(k0, k1, 0u, (uint32_t)idx, &a, &b);
  bits = a ^ b;
#else
  const uint32_t half = (uint32_t)(kN * kD) / 2u;
  uint32_t a, b;
  if ((uint32_t)idx < half) {
    tf2x32(k0, k1, (uint32_t)idx, (uint32_t)idx + half, &a, &b);
    bits = a;
  } else {
    tf2x32(k0, k1, (uint32_t)idx - half, (uint32_t)idx, &a, &b);
    bits = b;
  }
#endif
  float u = jax_uniform01(bits);
  // match jnp.where(u < 0.9, h / 0.9f, 0)  (p as float32; IEEE f32 division)
  out[idx] = (u < 0.9f) ? (in[idx] / 0.9f) : 0.0f;
}

// Edge-parallel scatter-add SpMM: 16 threads per edge, each does a float4
// gather from h[src] and 4 fp32 atomics into out[dst].
__global__ void spmm_k(const int* __restrict__ src, const int* __restrict__ dst,
                       const float* __restrict__ val, const float* __restrict__ h,
                       float* __restrict__ outp) {
  long tid = (long)blockIdx.x * blockDim.x + threadIdx.x;
  if (tid >= (long)kE * 16) return;
  int e = (int)(tid >> 4), q = (int)(tid & 15);
  int s = src[e], d = dst[e];
  float v = val[e];
  const float4 hv = *reinterpret_cast<const float4*>(h + (size_t)s * kD + q * 4);
  float* op = outp + (size_t)d * kD + q * 4;
  atomicAdd(op + 0, v * hv.x);
  atomicAdd(op + 1, v * hv.y);
  atomicAdd(op + 2, v * hv.z);
  atomicAdd(op + 3, v * hv.w);
}

__global__ void acc_add_k(float* __restrict__ acc, const float* __restrict__ h) {
  int idx = blockIdx.x * blockDim.x + threadIdx.x;
  if (idx >= kN * kD) return;
  acc[idx] += h[idx];
}

__global__ void scale_k(float* __restrict__ acc) {
  int idx = blockIdx.x * blockDim.x + threadIdx.x;
  if (idx >= kN * kD) return;
  acc[idx] *= 0.25f;
}

extern "C" void kernel_launch(void* const* d_in, const int* in_sizes, int n_in,
                              void* d_out, int out_size, void* d_ws, size_t ws_size,
                              hipStream_t stream) {
  const int* x = (const int*)d_in[0];
  const int* esrc = (const int*)d_in[1];
  const int* edst = (const int*)d_in[2];
  const float* evals = (const float*)d_in[3];
  const float* w = (const float*)d_in[4];
  float* acc = (float*)d_out;

  size_t bufElems = (size_t)kN * kD;
  float* hA = (float*)d_ws;
  float* hB = hA + bufElems;
  float* hC = hB + bufElems;

  // Host-side JAX key derivation: key(1) = (0,1); split into dk1,dk2,dk3.
  uint32_t dk[3][2];
#if JAX_PARTITIONABLE
  for (int i = 0; i < 3; ++i) tf2x32(0u, 1u, 0u, (uint32_t)i, &dk[i][0], &dk[i][1]);
#else
  uint32_t a[3], b[3];
  for (int i = 0; i < 3; ++i)
    tf2x32(0u, 1u, (uint32_t)i, (uint32_t)(i + 3), &a[i], &b[i]);
  // out = [a0,a1,a2,b0,b1,b2] reshaped (3,2)
  dk[0][0] = a[0]; dk[0][1] = a[1];
  dk[1][0] = a[2]; dk[1][1] = b[0];
  dk[2][0] = b[1]; dk[2][1] = b[2];
#endif

  const int threads = 256;
  const int gridND = (kN * kD + threads - 1) / threads;
  const long spmmThreads = (long)kE * 16;
  const int gridSp = (int)((spmmThreads + threads - 1) / threads);

  init_k<<<gridND, threads, 0, stream>>>(x, w, hA, acc);

  for (int L = 0; L < 3; ++L) {
    dropout_k<<<gridND, threads, 0, stream>>>(hA, hB, dk[L][0], dk[L][1]);
    hipMemsetAsync(hC, 0, bufElems * sizeof(float), stream);
    spmm_k<<<gridSp, threads, 0, stream>>>(esrc, edst, evals, hB, hC);
    acc_add_k<<<gridND, threads, 0, stream>>>(acc, hC);
    float* t = hA; hA = hC; hC = t;
  }
  scale_k<<<gridND, threads, 0, stream>>>(acc);
}

// Round 2
// 362.499 us; speedup vs baseline: 5.8230x; 5.8230x over previous
//
#include <hip/hip_runtime.h>
#include <stdint.h>

static const int kN = 50000;
static const int kD = 64;
static const int kE = 800000;
static const int kScanBlk = 256;
static const int kNB = (kN + kScanBlk - 1) / kScanBlk;  // 196

#define TFR(x0, x1, r)                                    \
  {                                                       \
    x0 += x1;                                             \
    x1 = ((x1 << (r)) | (x1 >> (32 - (r))));              \
    x1 ^= x0;                                             \
  }

// Threefry-2x32, 20 rounds, JAX key schedule (partitionable mode verified R1).
__host__ __device__ inline void tf2x32(uint32_t k0, uint32_t k1, uint32_t x0,
                                       uint32_t x1, uint32_t* o0, uint32_t* o1) {
  uint32_t k2 = k0 ^ k1 ^ 0x1BD11BDAu;
  x0 += k0; x1 += k1;
  TFR(x0, x1, 13) TFR(x0, x1, 15) TFR(x0, x1, 26) TFR(x0, x1, 6)
  x0 += k1; x1 += k2 + 1u;
  TFR(x0, x1, 17) TFR(x0, x1, 29) TFR(x0, x1, 16) TFR(x0, x1, 24)
  x0 += k2; x1 += k0 + 2u;
  TFR(x0, x1, 13) TFR(x0, x1, 15) TFR(x0, x1, 26) TFR(x0, x1, 6)
  x0 += k0; x1 += k1 + 3u;
  TFR(x0, x1, 17) TFR(x0, x1, 29) TFR(x0, x1, 16) TFR(x0, x1, 24)
  x0 += k1; x1 += k2 + 4u;
  TFR(x0, x1, 13) TFR(x0, x1, 15) TFR(x0, x1, 26) TFR(x0, x1, 6)
  x0 += k2; x1 += k0 + 5u;
  *o0 = x0; *o1 = x1;
}

__device__ inline float jax_dropout(float h, uint32_t k0, uint32_t k1, uint32_t idx) {
  uint32_t a, b;
  tf2x32(k0, k1, 0u, idx, &a, &b);
  uint32_t bits = a ^ b;
  float u = __uint_as_float((bits >> 9) | 0x3f800000u) - 1.0f;
  return (u < 0.9f) ? (h / 0.9f) : 0.0f;
}

// ---------------- CSR build ----------------
__global__ void hist_k(const int* __restrict__ dst, int* __restrict__ counts) {
  int e = blockIdx.x * blockDim.x + threadIdx.x;
  if (e < kE) atomicAdd(&counts[dst[e]], 1);
}

// Per-block exclusive scan; writes local exclusive scan into offsets, block sums out.
__global__ void scanA_k(const int* __restrict__ counts, int* __restrict__ offsets,
                        int* __restrict__ blocksums) {
  __shared__ int sm[2][kScanBlk];
  int t = threadIdx.x;
  int i = blockIdx.x * kScanBlk + t;
  int v = (i < kN) ? counts[i] : 0;
  int p = 0;
  sm[0][t] = v;
  __syncthreads();
  for (int off = 1; off < kScanBlk; off <<= 1) {
    int q = p ^ 1;
    sm[q][t] = sm[p][t] + ((t >= off) ? sm[p][t - off] : 0);
    __syncthreads();
    p = q;
  }
  if (i < kN) offsets[i] = sm[p][t] - v;  // exclusive within block
  if (t == kScanBlk - 1) blocksums[blockIdx.x] = sm[p][t];
}

// Single block scans the (<=256) block sums -> exclusive block bases.
__global__ void scanB_k(const int* __restrict__ blocksums, int* __restrict__ blockbase) {
  __shared__ int sm[2][kScanBlk];
  int t = threadIdx.x;
  int v = (t < kNB) ? blocksums[t] : 0;
  int p = 0;
  sm[0][t] = v;
  __syncthreads();
  for (int off = 1; off < kScanBlk; off <<= 1) {
    int q = p ^ 1;
    sm[q][t] = sm[p][t] + ((t >= off) ? sm[p][t - off] : 0);
    __syncthreads();
    p = q;
  }
  blockbase[t] = sm[p][t] - v;
}

__global__ void scanC_k(int* __restrict__ offsets, const int* __restrict__ blockbase,
                        int* __restrict__ cursor) {
  int i = blockIdx.x * kScanBlk + threadIdx.x;
  if (i < kN) {
    int o = offsets[i] + blockbase[blockIdx.x];
    offsets[i] = o;
    cursor[i] = o;
  }
}

__global__ void scatter_k(const int* __restrict__ src, const int* __restrict__ dst,
                          const float* __restrict__ val, int* __restrict__ cursor,
                          int* __restrict__ csr_src, float* __restrict__ csr_val) {
  int e = blockIdx.x * blockDim.x + threadIdx.x;
  if (e >= kE) return;
  int d = dst[e];
  int pos = atomicAdd(&cursor[d], 1);
  csr_src[pos] = src[e];
  csr_val[pos] = val[e];
}

// ---------------- pipeline ----------------
// acc = h0 = embed[x]; hB = dropout(h0, dk1)
__global__ void init_k(const int* __restrict__ x, const float* __restrict__ w,
                       float* __restrict__ acc, float* __restrict__ hB,
                       uint32_t k0, uint32_t k1) {
  int idx = blockIdx.x * blockDim.x + threadIdx.x;
  if (idx >= kN * kD) return;
  int n = idx >> 6, d = idx & 63;
  float v = w[(size_t)x[n] * kD + d];
  acc[idx] = v;
  hB[idx] = jax_dropout(v, k0, k1, (uint32_t)idx);
}

// One wave per dst node; lane = feature dim. sum = Sum val*hIn[src][lane].
// Epilogue: acc += sum (or final (acc+sum)*0.25), hOut = dropout(sum) for next layer.
__global__ void layer_k(const int* __restrict__ csr_src, const float* __restrict__ csr_val,
                        const int* __restrict__ offsets, const int* __restrict__ counts,
                        const float* __restrict__ hIn, float* __restrict__ acc,
                        float* __restrict__ hOut, uint32_t k0, uint32_t k1, int last) {
  int gtid = blockIdx.x * blockDim.x + threadIdx.x;
  int node = gtid >> 6;
  int lane = threadIdx.x & 63;
  if (node >= kN) return;
  int beg = offsets[node];
  int end = beg + counts[node];
  float sum = 0.0f;
  for (int e = beg; e < end; ++e) {
    int s = csr_src[e];       // wave-uniform broadcast load
    float v = csr_val[e];
    sum += v * hIn[(s << 6) + lane];  // coalesced 256B row gather
  }
  int idx = (node << 6) + lane;
  if (last) {
    acc[idx] = (acc[idx] + sum) * 0.25f;
  } else {
    acc[idx] += sum;
    hOut[idx] = jax_dropout(sum, k0, k1, (uint32_t)idx);
  }
}

extern "C" void kernel_launch(void* const* d_in, const int* in_sizes, int n_in,
                              void* d_out, int out_size, void* d_ws, size_t ws_size,
                              hipStream_t stream) {
  const int* x = (const int*)d_in[0];
  const int* esrc = (const int*)d_in[1];
  const int* edst = (const int*)d_in[2];
  const float* evals = (const float*)d_in[3];
  const float* w = (const float*)d_in[4];
  float* acc = (float*)d_out;

  // ---- workspace layout (~32.6 MB) ----
  size_t nd = (size_t)kN * kD;
  float* hB0 = (float*)d_ws;
  float* hB1 = hB0 + nd;
  int* counts = (int*)(hB1 + nd);
  int* offsets = counts + kN;
  int* cursor = offsets + kN;
  int* blocksums = cursor + kN;        // 256 slots
  int* blockbase = blocksums + 256;    // 256 slots
  int* csr_src = blockbase + 256;
  float* csr_val = (float*)(csr_src + kE);

  // JAX key derivation: key(1)=(0,1) -> split 3 (partitionable, verified R1).
  uint32_t dk[3][2];
  for (int i = 0; i < 3; ++i) tf2x32(0u, 1u, 0u, (uint32_t)i, &dk[i][0], &dk[i][1]);

  const int T = 256;
  const int gridND = (int)((nd + T - 1) / T);
  const int gridE = (kE + T - 1) / T;

  // CSR build (deterministic work each call)
  hipMemsetAsync(counts, 0, (size_t)kN * sizeof(int), stream);
  hist_k<<<gridE, T, 0, stream>>>(edst, counts);
  scanA_k<<<kNB, kScanBlk, 0, stream>>>(counts, offsets, blocksums);
  scanB_k<<<1, kScanBlk, 0, stream>>>(blocksums, blockbase);
  scanC_k<<<kNB, kScanBlk, 0, stream>>>(offsets, blockbase, cursor);
  scatter_k<<<gridE, T, 0, stream>>>(esrc, edst, evals, cursor, csr_src, csr_val);

  // init: acc = h0, hB0 = dropout(h0, dk1)
  init_k<<<gridND, T, 0, stream>>>(x, w, acc, hB0, dk[0][0], dk[0][1]);

  // 3 layers, one wave per node
  const int gridL = (int)(((size_t)kN * 64 + T - 1) / T);
  layer_k<<<gridL, T, 0, stream>>>(csr_src, csr_val, offsets, counts, hB0, acc, hB1,
                                   dk[1][0], dk[1][1], 0);
  layer_k<<<gridL, T, 0, stream>>>(csr_src, csr_val, offsets, counts, hB1, acc, hB0,
                                   dk[2][0], dk[2][1], 0);
  layer_k<<<gridL, T, 0, stream>>>(csr_src, csr_val, offsets, counts, hB0, acc, hB1,
                                   0u, 0u, 1);
}

// Round 3
// 233.203 us; speedup vs baseline: 9.0516x; 1.5544x over previous
//
#include <hip/hip_runtime.h>
#include <stdint.h>

static const int kN = 50000;
static const int kD = 64;
static const int kE = 800000;
static const int kScanBlk = 256;
static const int kNB = (kN + kScanBlk - 1) / kScanBlk;  // 196

#define TFR(x0, x1, r)                                    \
  {                                                       \
    x0 += x1;                                             \
    x1 = ((x1 << (r)) | (x1 >> (32 - (r))));              \
    x1 ^= x0;                                             \
  }

// Threefry-2x32, 20 rounds, JAX key schedule (partitionable mode verified R1).
__host__ __device__ inline void tf2x32(uint32_t k0, uint32_t k1, uint32_t x0,
                                       uint32_t x1, uint32_t* o0, uint32_t* o1) {
  uint32_t k2 = k0 ^ k1 ^ 0x1BD11BDAu;
  x0 += k0; x1 += k1;
  TFR(x0, x1, 13) TFR(x0, x1, 15) TFR(x0, x1, 26) TFR(x0, x1, 6)
  x0 += k1; x1 += k2 + 1u;
  TFR(x0, x1, 17) TFR(x0, x1, 29) TFR(x0, x1, 16) TFR(x0, x1, 24)
  x0 += k2; x1 += k0 + 2u;
  TFR(x0, x1, 13) TFR(x0, x1, 15) TFR(x0, x1, 26) TFR(x0, x1, 6)
  x0 += k0; x1 += k1 + 3u;
  TFR(x0, x1, 17) TFR(x0, x1, 29) TFR(x0, x1, 16) TFR(x0, x1, 24)
  x0 += k1; x1 += k2 + 4u;
  TFR(x0, x1, 13) TFR(x0, x1, 15) TFR(x0, x1, 26) TFR(x0, x1, 6)
  x0 += k2; x1 += k0 + 5u;
  *o0 = x0; *o1 = x1;
}

__device__ inline float jax_dropout(float h, uint32_t k0, uint32_t k1, uint32_t idx) {
  uint32_t a, b;
  tf2x32(k0, k1, 0u, idx, &a, &b);
  uint32_t bits = a ^ b;
  float u = __uint_as_float((bits >> 9) | 0x3f800000u) - 1.0f;
  return (u < 0.9f) ? (h / 0.9f) : 0.0f;
}

// ---------------- CSR build ----------------
__global__ void hist_k(const int* __restrict__ dst, int* __restrict__ counts) {
  int e = blockIdx.x * blockDim.x + threadIdx.x;
  if (e < kE) atomicAdd(&counts[dst[e]], 1);
}

__global__ void scanA_k(const int* __restrict__ counts, int* __restrict__ offsets,
                        int* __restrict__ blocksums) {
  __shared__ int sm[2][kScanBlk];
  int t = threadIdx.x;
  int i = blockIdx.x * kScanBlk + t;
  int v = (i < kN) ? counts[i] : 0;
  int p = 0;
  sm[0][t] = v;
  __syncthreads();
  for (int off = 1; off < kScanBlk; off <<= 1) {
    int q = p ^ 1;
    sm[q][t] = sm[p][t] + ((t >= off) ? sm[p][t - off] : 0);
    __syncthreads();
    p = q;
  }
  if (i < kN) offsets[i] = sm[p][t] - v;
  if (t == kScanBlk - 1) blocksums[blockIdx.x] = sm[p][t];
}

__global__ void scanB_k(const int* __restrict__ blocksums, int* __restrict__ blockbase) {
  __shared__ int sm[2][kScanBlk];
  int t = threadIdx.x;
  int v = (t < kNB) ? blocksums[t] : 0;
  int p = 0;
  sm[0][t] = v;
  __syncthreads();
  for (int off = 1; off < kScanBlk; off <<= 1) {
    int q = p ^ 1;
    sm[q][t] = sm[p][t] + ((t >= off) ? sm[p][t - off] : 0);
    __syncthreads();
    p = q;
  }
  blockbase[t] = sm[p][t] - v;
}

__global__ void scanC_k(int* __restrict__ offsets, const int* __restrict__ blockbase,
                        int* __restrict__ cursor) {
  int i = blockIdx.x * kScanBlk + threadIdx.x;
  if (i < kN) {
    int o = offsets[i] + blockbase[blockIdx.x];
    offsets[i] = o;
    cursor[i] = o;
  }
}

// Packed (src, val-bits) payload: one 8B write per edge, one 8B load per edge later.
__global__ void scatter_k(const int* __restrict__ src, const int* __restrict__ dst,
                          const float* __restrict__ val, int* __restrict__ cursor,
                          int2* __restrict__ csr_sv) {
  int e = blockIdx.x * blockDim.x + threadIdx.x;
  if (e >= kE) return;
  int d = dst[e];
  int pos = atomicAdd(&cursor[d], 1);
  csr_sv[pos] = make_int2(src[e], __float_as_int(val[e]));
}

// ---------------- pipeline ----------------
__global__ void init_k(const int* __restrict__ x, const float* __restrict__ w,
                       float* __restrict__ acc, float* __restrict__ hB,
                       uint32_t k0, uint32_t k1) {
  int idx = blockIdx.x * blockDim.x + threadIdx.x;
  if (idx >= kN * kD) return;
  int n = idx >> 6, d = idx & 63;
  float v = w[(size_t)x[n] * kD + d];
  acc[idx] = v;
  hB[idx] = jax_dropout(v, k0, k1, (uint32_t)idx);
}

// One wave per dst node; lane = dim. Edge metadata via wave-uniform (scalar)
// loads; 16 row-gathers issued back-to-back per chunk for 16-way MLP.
__global__ __launch_bounds__(256) void layer_k(
    const int2* __restrict__ csr_sv, const int* __restrict__ offsets,
    const int* __restrict__ counts, const float* __restrict__ hIn,
    float* __restrict__ acc, float* __restrict__ hOut,
    uint32_t k0, uint32_t k1, int last) {
  int gtid = blockIdx.x * blockDim.x + threadIdx.x;
  int node = gtid >> 6;
  int lane = threadIdx.x & 63;
  if (node >= kN) return;
  int beg = __builtin_amdgcn_readfirstlane(offsets[node]);
  int deg = __builtin_amdgcn_readfirstlane(counts[node]);
  float sum = 0.0f;
  for (int c = 0; c < deg; c += 16) {
    const int2* p = csr_sv + beg + c;  // wave-uniform address
    int rem = deg - c;                 // wave-uniform
    float g[16], vv[16];
#pragma unroll
    for (int j = 0; j < 16; ++j) {
      int2 sv = p[j];  // uniform -> scalar load; +pad keeps over-read in-bounds
      int s = (j < rem) ? sv.x : 0;
      vv[j] = (j < rem) ? __int_as_float(sv.y) : 0.0f;
      g[j] = hIn[(s << 6) + lane];  // coalesced 256B row gather, 16 in flight
    }
#pragma unroll
    for (int j = 0; j < 16; ++j) sum += vv[j] * g[j];
  }
  int idx = (node << 6) + lane;
  if (last) {
    acc[idx] = (acc[idx] + sum) * 0.25f;
  } else {
    acc[idx] += sum;
    hOut[idx] = jax_dropout(sum, k0, k1, (uint32_t)idx);
  }
}

extern "C" void kernel_launch(void* const* d_in, const int* in_sizes, int n_in,
                              void* d_out, int out_size, void* d_ws, size_t ws_size,
                              hipStream_t stream) {
  const int* x = (const int*)d_in[0];
  const int* esrc = (const int*)d_in[1];
  const int* edst = (const int*)d_in[2];
  const float* evals = (const float*)d_in[3];
  const float* w = (const float*)d_in[4];
  float* acc = (float*)d_out;

  // ---- workspace layout (~32.7 MB) ----
  size_t nd = (size_t)kN * kD;
  float* hB0 = (float*)d_ws;
  float* hB1 = hB0 + nd;
  int* counts = (int*)(hB1 + nd);
  int* offsets = counts + kN;
  int* cursor = offsets + kN;
  int* blocksums = cursor + kN;      // 256 slots
  int* blockbase = blocksums + 256;  // 256 slots
  int2* csr_sv = (int2*)(blockbase + 256);  // kE + 16 pad entries

  // JAX key derivation: key(1)=(0,1) -> split 3 (partitionable, verified R1).
  uint32_t dk[3][2];
  for (int i = 0; i < 3; ++i) tf2x32(0u, 1u, 0u, (uint32_t)i, &dk[i][0], &dk[i][1]);

  const int T = 256;
  const int gridND = (int)((nd + T - 1) / T);
  const int gridE = (kE + T - 1) / T;

  // CSR build (recomputed every call; deterministic work)
  hipMemsetAsync(counts, 0, (size_t)kN * sizeof(int), stream);
  hipMemsetAsync(csr_sv + kE, 0, 16 * sizeof(int2), stream);  // pad for uniform over-read
  hist_k<<<gridE, T, 0, stream>>>(edst, counts);
  scanA_k<<<kNB, kScanBlk, 0, stream>>>(counts, offsets, blocksums);
  scanB_k<<<1, kScanBlk, 0, stream>>>(blocksums, blockbase);
  scanC_k<<<kNB, kScanBlk, 0, stream>>>(offsets, blockbase, cursor);
  scatter_k<<<gridE, T, 0, stream>>>(esrc, edst, evals, cursor, csr_sv);

  init_k<<<gridND, T, 0, stream>>>(x, w, acc, hB0, dk[0][0], dk[0][1]);

  const int gridL = (int)(((size_t)kN * 64 + T - 1) / T);
  layer_k<<<gridL, T, 0, stream>>>(csr_sv, offsets, counts, hB0, acc, hB1,
                                   dk[1][0], dk[1][1], 0);
  layer_k<<<gridL, T, 0, stream>>>(csr_sv, offsets, counts, hB1, acc, hB0,
                                   dk[2][0], dk[2][1], 0);
  layer_k<<<gridL, T, 0, stream>>>(csr_sv, offsets, counts, hB0, acc, hB1,
                                   0u, 0u, 1);
}